// Round 3
// baseline (189.198 us; speedup 1.0000x reference)
//
#include <hip/hip_runtime.h>

// Bundle-adjustment reprojection residual, 4 observations per thread.
//   p_cam = p + 2*qv x (qv x p + qw*p) + t ;  res = K-proj(p_cam) - obs
// Memory-latency-bound gather kernel: 16B vector loads for the streaming
// arrays (nontemporal -> keep L2 for the 6MB point table), 4 independent
// point/pose gathers in flight per thread.
//
// NOTE: __builtin_nontemporal_* requires Clang ext_vector_type, not HIP's
// struct-based float4/int4 (round-2 compile failure).

typedef float vfloat4 __attribute__((ext_vector_type(4)));
typedef int   vint4   __attribute__((ext_vector_type(4)));

__global__ __launch_bounds__(256) void resid_kernel4(
    const float* __restrict__ obs,    // [n*2]
    const float* __restrict__ Kmat,   // [9]
    const float* __restrict__ poses,  // [N_CAM*7] t(3), qv(3), qw
    const float* __restrict__ points, // [N_PTS*3]
    const int*   __restrict__ cidx,   // [n]
    const int*   __restrict__ pidx,   // [n]
    float*       __restrict__ out,    // [n*2]
    int n)
{
    int t = blockIdx.x * blockDim.x + threadIdx.x;
    int base = t * 4;

    // K is uniform: scalar loads, broadcast.
    float fx = Kmat[0], cx = Kmat[2];
    float fy = Kmat[4], cy = Kmat[5];

    if (base + 4 <= n) {
        // ---- streaming loads (nontemporal: don't pollute L2) ----
        vint4   c4  = __builtin_nontemporal_load((const vint4*)(cidx + base));
        vint4   p4  = __builtin_nontemporal_load((const vint4*)(pidx + base));
        vfloat4 o01 = __builtin_nontemporal_load((const vfloat4*)(obs + 2 * base));
        vfloat4 o23 = __builtin_nontemporal_load((const vfloat4*)(obs + 2 * base + 4));

        int cc[4] = {c4.x, c4.y, c4.z, c4.w};
        int pp[4] = {p4.x, p4.y, p4.z, p4.w};

        // ---- issue all gathers before any compute (max MLP) ----
        float P[4][3];
        #pragma unroll
        for (int k = 0; k < 4; ++k) {
            const float* pt = points + 3 * pp[k];
            P[k][0] = pt[0]; P[k][1] = pt[1]; P[k][2] = pt[2];
        }
        float Q[4][7];
        #pragma unroll
        for (int k = 0; k < 4; ++k) {
            const float* ps = poses + 7 * cc[k];
            #pragma unroll
            for (int j = 0; j < 7; ++j) Q[k][j] = ps[j];
        }

        float res[8];
        #pragma unroll
        for (int k = 0; k < 4; ++k) {
            float px = P[k][0], py = P[k][1], pz = P[k][2];
            float tx = Q[k][0], ty = Q[k][1], tz = Q[k][2];
            float qx = Q[k][3], qy = Q[k][4], qz = Q[k][5], qw = Q[k][6];

            float ux = qy * pz - qz * py;
            float uy = qz * px - qx * pz;
            float uz = qx * py - qy * px;
            float wx = ux + qw * px;
            float wy = uy + qw * py;
            float wz = uz + qw * pz;
            float ccx = qy * wz - qz * wy;
            float ccy = qz * wx - qx * wz;
            float ccz = qx * wy - qy * wx;
            float X = px + 2.0f * ccx + tx;
            float Y = py + 2.0f * ccy + ty;
            float Z = pz + 2.0f * ccz + tz;

            float invz = 1.0f / Z;
            res[2 * k]     = fx * X * invz + cx;
            res[2 * k + 1] = fy * Y * invz + cy;
        }

        vfloat4 r0 = {res[0] - o01.x, res[1] - o01.y, res[2] - o01.z, res[3] - o01.w};
        vfloat4 r1 = {res[4] - o23.x, res[5] - o23.y, res[6] - o23.z, res[7] - o23.w};
        __builtin_nontemporal_store(r0, (vfloat4*)(out + 2 * base));
        __builtin_nontemporal_store(r1, (vfloat4*)(out + 2 * base + 4));
    } else {
        // tail (n not divisible by 4): scalar path
        for (int i = base; i < n; ++i) {
            int c = cidx[i];
            int p = pidx[i];
            const float* ps = poses + 7 * c;
            const float* pt = points + 3 * p;
            float px = pt[0], py = pt[1], pz = pt[2];
            float tx = ps[0], ty = ps[1], tz = ps[2];
            float qx = ps[3], qy = ps[4], qz = ps[5], qw = ps[6];

            float ux = qy * pz - qz * py;
            float uy = qz * px - qx * pz;
            float uz = qx * py - qy * px;
            float wx = ux + qw * px;
            float wy = uy + qw * py;
            float wz = uz + qw * pz;
            float ccx = qy * wz - qz * wy;
            float ccy = qz * wx - qx * wz;
            float ccz = qx * wy - qy * wx;
            float X = px + 2.0f * ccx + tx;
            float Y = py + 2.0f * ccy + ty;
            float Z = pz + 2.0f * ccz + tz;

            float invz = 1.0f / Z;
            out[2 * i]     = fx * X * invz + cx - obs[2 * i];
            out[2 * i + 1] = fy * Y * invz + cy - obs[2 * i + 1];
        }
    }
}

extern "C" void kernel_launch(void* const* d_in, const int* in_sizes, int n_in,
                              void* d_out, int out_size, void* d_ws, size_t ws_size,
                              hipStream_t stream) {
    const float* obs    = (const float*)d_in[0];
    const float* Kmat   = (const float*)d_in[1];
    const float* poses  = (const float*)d_in[2];
    const float* points = (const float*)d_in[3];
    const int*   cidx   = (const int*)d_in[4];
    const int*   pidx   = (const int*)d_in[5];
    float*       out    = (float*)d_out;

    int n = in_sizes[4];  // N_OBS
    int block = 256;
    int per_block = block * 4;
    int grid = (n + per_block - 1) / per_block;
    resid_kernel4<<<grid, block, 0, stream>>>(obs, Kmat, poses, points, cidx, pidx, out, n);
}

// Round 4
// 188.525 us; speedup vs baseline: 1.0036x; 1.0036x over previous
//
#include <hip/hip_runtime.h>

// Bundle-adjustment reprojection residual.
// R3 post-mortem: VMEM-instruction-bound (46 divergent VMEM insts/thread,
// ~1 inst/cy/CU == measured runtime; HBM only 30%). Fix: repack gather
// tables into 16B-aligned rows in d_ws so each point gather is ONE
// global_load_dwordx4 (never straddling a cacheline) and each pose is TWO
// dwordx4 instead of 7 scalar dwords. Per-thread VMEM: 46 -> 18.
// Prep kernels rerun every launch (ws re-poisoned to 0xAA by harness).

typedef float vfloat4 __attribute__((ext_vector_type(4)));
typedef int   vint4   __attribute__((ext_vector_type(4)));

// ---- prep: points [N_PTS*3] -> points_pad [N_PTS*4] (16B rows) ----
__global__ __launch_bounds__(256) void pad_points(
    const float* __restrict__ src, vfloat4* __restrict__ dst, int n_pts)
{
    int i = blockIdx.x * blockDim.x + threadIdx.x;
    if (i >= n_pts) return;
    const float* s = src + 3 * i;
    vfloat4 v = {s[0], s[1], s[2], 0.0f};
    dst[i] = v;
}

// ---- prep: poses [N_CAM*7] -> poses_pad [N_CAM*8] (two 16B rows) ----
__global__ __launch_bounds__(256) void pad_poses(
    const float* __restrict__ src, vfloat4* __restrict__ dst, int n_cam)
{
    int i = blockIdx.x * blockDim.x + threadIdx.x;
    if (i >= n_cam) return;
    const float* s = src + 7 * i;
    vfloat4 a = {s[0], s[1], s[2], s[3]};   // t.xyz, qx
    vfloat4 b = {s[4], s[5], s[6], 0.0f};   // qy, qz, qw
    dst[2 * i]     = a;
    dst[2 * i + 1] = b;
}

__global__ __launch_bounds__(256) void resid_kernel4p(
    const float*   __restrict__ obs,        // [n*2]
    const float*   __restrict__ Kmat,       // [9]
    const vfloat4* __restrict__ poses_pad,  // [N_CAM*2]
    const vfloat4* __restrict__ points_pad, // [N_PTS]
    const int*     __restrict__ cidx,       // [n]
    const int*     __restrict__ pidx,       // [n]
    float*         __restrict__ out,        // [n*2]
    int n)
{
    int t = blockIdx.x * blockDim.x + threadIdx.x;
    int base = t * 4;

    float fx = Kmat[0], cx = Kmat[2];
    float fy = Kmat[4], cy = Kmat[5];

    if (base + 4 <= n) {
        vint4   c4  = __builtin_nontemporal_load((const vint4*)(cidx + base));
        vint4   p4  = __builtin_nontemporal_load((const vint4*)(pidx + base));
        vfloat4 o01 = __builtin_nontemporal_load((const vfloat4*)(obs + 2 * base));
        vfloat4 o23 = __builtin_nontemporal_load((const vfloat4*)(obs + 2 * base + 4));

        int cc[4] = {c4.x, c4.y, c4.z, c4.w};
        int pp[4] = {p4.x, p4.y, p4.z, p4.w};

        // issue all gathers up front (max loads in flight)
        vfloat4 P[4], QA[4], QB[4];
        #pragma unroll
        for (int k = 0; k < 4; ++k) P[k] = points_pad[pp[k]];
        #pragma unroll
        for (int k = 0; k < 4; ++k) {
            QA[k] = poses_pad[2 * cc[k]];
            QB[k] = poses_pad[2 * cc[k] + 1];
        }

        float res[8];
        #pragma unroll
        for (int k = 0; k < 4; ++k) {
            float px = P[k].x, py = P[k].y, pz = P[k].z;
            float tx = QA[k].x, ty = QA[k].y, tz = QA[k].z;
            float qx = QA[k].w, qy = QB[k].x, qz = QB[k].y, qw = QB[k].z;

            float ux = qy * pz - qz * py;
            float uy = qz * px - qx * pz;
            float uz = qx * py - qy * px;
            float wx = ux + qw * px;
            float wy = uy + qw * py;
            float wz = uz + qw * pz;
            float ccx = qy * wz - qz * wy;
            float ccy = qz * wx - qx * wz;
            float ccz = qx * wy - qy * wx;
            float X = px + 2.0f * ccx + tx;
            float Y = py + 2.0f * ccy + ty;
            float Z = pz + 2.0f * ccz + tz;

            float invz = 1.0f / Z;
            res[2 * k]     = fx * X * invz + cx;
            res[2 * k + 1] = fy * Y * invz + cy;
        }

        vfloat4 r0 = {res[0] - o01.x, res[1] - o01.y, res[2] - o01.z, res[3] - o01.w};
        vfloat4 r1 = {res[4] - o23.x, res[5] - o23.y, res[6] - o23.z, res[7] - o23.w};
        __builtin_nontemporal_store(r0, (vfloat4*)(out + 2 * base));
        __builtin_nontemporal_store(r1, (vfloat4*)(out + 2 * base + 4));
    } else {
        for (int i = base; i < n; ++i) {
            vfloat4 P  = points_pad[pidx[i]];
            vfloat4 QA = poses_pad[2 * cidx[i]];
            vfloat4 QB = poses_pad[2 * cidx[i] + 1];
            float px = P.x, py = P.y, pz = P.z;
            float tx = QA.x, ty = QA.y, tz = QA.z;
            float qx = QA.w, qy = QB.x, qz = QB.y, qw = QB.z;

            float ux = qy * pz - qz * py;
            float uy = qz * px - qx * pz;
            float uz = qx * py - qy * px;
            float wx = ux + qw * px;
            float wy = uy + qw * py;
            float wz = uz + qw * pz;
            float ccx = qy * wz - qz * wy;
            float ccy = qz * wx - qx * wz;
            float ccz = qx * wy - qy * wx;
            float X = px + 2.0f * ccx + tx;
            float Y = py + 2.0f * ccy + ty;
            float Z = pz + 2.0f * ccz + tz;

            float invz = 1.0f / Z;
            out[2 * i]     = fx * X * invz + cx - obs[2 * i];
            out[2 * i + 1] = fy * Y * invz + cy - obs[2 * i + 1];
        }
    }
}

// fallback (ws too small): round-3 kernel, scalar gathers from raw tables
__global__ __launch_bounds__(256) void resid_fallback(
    const float* __restrict__ obs, const float* __restrict__ Kmat,
    const float* __restrict__ poses, const float* __restrict__ points,
    const int* __restrict__ cidx, const int* __restrict__ pidx,
    float* __restrict__ out, int n)
{
    int i = blockIdx.x * blockDim.x + threadIdx.x;
    if (i >= n) return;
    const float* ps = poses + 7 * cidx[i];
    const float* pt = points + 3 * pidx[i];
    float px = pt[0], py = pt[1], pz = pt[2];
    float tx = ps[0], ty = ps[1], tz = ps[2];
    float qx = ps[3], qy = ps[4], qz = ps[5], qw = ps[6];
    float ux = qy * pz - qz * py;
    float uy = qz * px - qx * pz;
    float uz = qx * py - qy * px;
    float wx = ux + qw * px;
    float wy = uy + qw * py;
    float wz = uz + qw * pz;
    float ccx = qy * wz - qz * wy;
    float ccy = qz * wx - qx * wz;
    float ccz = qx * wy - qy * wx;
    float X = px + 2.0f * ccx + tx;
    float Y = py + 2.0f * ccy + ty;
    float Z = pz + 2.0f * ccz + tz;
    float invz = 1.0f / Z;
    out[2 * i]     = Kmat[0] * X * invz + Kmat[2] - obs[2 * i];
    out[2 * i + 1] = Kmat[4] * Y * invz + Kmat[5] - obs[2 * i + 1];
}

extern "C" void kernel_launch(void* const* d_in, const int* in_sizes, int n_in,
                              void* d_out, int out_size, void* d_ws, size_t ws_size,
                              hipStream_t stream) {
    const float* obs    = (const float*)d_in[0];
    const float* Kmat   = (const float*)d_in[1];
    const float* poses  = (const float*)d_in[2];
    const float* points = (const float*)d_in[3];
    const int*   cidx   = (const int*)d_in[4];
    const int*   pidx   = (const int*)d_in[5];
    float*       out    = (float*)d_out;

    int n     = in_sizes[4];      // N_OBS
    int n_cam = in_sizes[2] / 7;  // 2000
    int n_pts = in_sizes[3] / 3;  // 500000

    size_t pts_bytes  = (size_t)n_pts * 16;
    size_t pose_bytes = (size_t)n_cam * 32;

    if (ws_size < pts_bytes + pose_bytes) {
        resid_fallback<<<(n + 255) / 256, 256, 0, stream>>>(
            obs, Kmat, poses, points, cidx, pidx, out, n);
        return;
    }

    vfloat4* points_pad = (vfloat4*)d_ws;
    vfloat4* poses_pad  = (vfloat4*)((char*)d_ws + pts_bytes);

    pad_points<<<(n_pts + 255) / 256, 256, 0, stream>>>(points, points_pad, n_pts);
    pad_poses<<<(n_cam + 255) / 256, 256, 0, stream>>>(poses, poses_pad, n_cam);

    int per_block = 256 * 4;
    int grid = (n + per_block - 1) / per_block;
    resid_kernel4p<<<grid, 256, 0, stream>>>(
        obs, Kmat, poses_pad, points_pad, cidx, pidx, out, n);
}

// Round 5
// 179.595 us; speedup vs baseline: 1.0535x; 1.0497x over previous
//
#include <hip/hip_runtime.h>

// Bundle-adjustment reprojection residual.
// R4 post-mortem: bound by divergent gather lane-requests (TA/L1/L2 pipe),
// not VMEM inst count, not HBM BW (39%). Fix: pose table (2000 x 32 B =
// 64000 B) lives in LDS, preloaded per block -> pose lookups move to the
// LDS pipe and overlap with point gathers. Vector-memory gather insts per
// thread: 12 -> 4. 1024-thread blocks keep 2 blocks/CU (32 waves, ~100%
// occupancy) despite 64 KB LDS.

typedef float vfloat4 __attribute__((ext_vector_type(4)));
typedef int   vint4   __attribute__((ext_vector_type(4)));

#define MAX_CAM 2000   // LDS pose table capacity (64000 B)

// ---- prep: points [N_PTS*3] -> points_pad [N_PTS*4] (16B rows) ----
__global__ __launch_bounds__(256) void pad_points(
    const float* __restrict__ src, vfloat4* __restrict__ dst, int n_pts)
{
    int i = blockIdx.x * blockDim.x + threadIdx.x;
    if (i >= n_pts) return;
    const float* s = src + 3 * i;
    vfloat4 v = {s[0], s[1], s[2], 0.0f};
    dst[i] = v;
}

// ---- prep: poses [N_CAM*7] -> poses_pad [N_CAM*8] (two 16B rows) ----
__global__ __launch_bounds__(256) void pad_poses(
    const float* __restrict__ src, vfloat4* __restrict__ dst, int n_cam)
{
    int i = blockIdx.x * blockDim.x + threadIdx.x;
    if (i >= n_cam) return;
    const float* s = src + 7 * i;
    vfloat4 a = {s[0], s[1], s[2], s[3]};   // t.xyz, qx
    vfloat4 b = {s[4], s[5], s[6], 0.0f};   // qy, qz, qw
    dst[2 * i]     = a;
    dst[2 * i + 1] = b;
}

__global__ __launch_bounds__(1024) void resid_lds(
    const float*   __restrict__ obs,        // [n*2]
    const float*   __restrict__ Kmat,       // [9]
    const vfloat4* __restrict__ poses_pad,  // [n_cam*2] 16B rows
    const vfloat4* __restrict__ points_pad, // [n_pts]
    const int*     __restrict__ cidx,       // [n]
    const int*     __restrict__ pidx,       // [n]
    float*         __restrict__ out,        // [n*2]
    int n, int n_cam)
{
    __shared__ vfloat4 sposes[2 * MAX_CAM];  // 64000 B

    // coalesced preload of the padded pose table (L2-hot source)
    int rows = 2 * n_cam;
    for (int r = threadIdx.x; r < rows; r += blockDim.x)
        sposes[r] = poses_pad[r];
    __syncthreads();

    int t = blockIdx.x * blockDim.x + threadIdx.x;
    int base = t * 4;

    float fx = Kmat[0], cx = Kmat[2];
    float fy = Kmat[4], cy = Kmat[5];

    if (base + 4 <= n) {
        vint4   c4  = __builtin_nontemporal_load((const vint4*)(cidx + base));
        vint4   p4  = __builtin_nontemporal_load((const vint4*)(pidx + base));
        vfloat4 o01 = __builtin_nontemporal_load((const vfloat4*)(obs + 2 * base));
        vfloat4 o23 = __builtin_nontemporal_load((const vfloat4*)(obs + 2 * base + 4));

        int cc[4] = {c4.x, c4.y, c4.z, c4.w};
        int pp[4] = {p4.x, p4.y, p4.z, p4.w};

        // point gathers: the only divergent vector-memory traffic
        vfloat4 P[4];
        #pragma unroll
        for (int k = 0; k < 4; ++k) P[k] = points_pad[pp[k]];

        // pose lookups from LDS (separate pipe, overlaps with gathers)
        vfloat4 QA[4], QB[4];
        #pragma unroll
        for (int k = 0; k < 4; ++k) {
            QA[k] = sposes[2 * cc[k]];
            QB[k] = sposes[2 * cc[k] + 1];
        }

        float res[8];
        #pragma unroll
        for (int k = 0; k < 4; ++k) {
            float px = P[k].x, py = P[k].y, pz = P[k].z;
            float tx = QA[k].x, ty = QA[k].y, tz = QA[k].z;
            float qx = QA[k].w, qy = QB[k].x, qz = QB[k].y, qw = QB[k].z;

            float ux = qy * pz - qz * py;
            float uy = qz * px - qx * pz;
            float uz = qx * py - qy * px;
            float wx = ux + qw * px;
            float wy = uy + qw * py;
            float wz = uz + qw * pz;
            float ccx = qy * wz - qz * wy;
            float ccy = qz * wx - qx * wz;
            float ccz = qx * wy - qy * wx;
            float X = px + 2.0f * ccx + tx;
            float Y = py + 2.0f * ccy + ty;
            float Z = pz + 2.0f * ccz + tz;

            float invz = 1.0f / Z;
            res[2 * k]     = fx * X * invz + cx;
            res[2 * k + 1] = fy * Y * invz + cy;
        }

        vfloat4 r0 = {res[0] - o01.x, res[1] - o01.y, res[2] - o01.z, res[3] - o01.w};
        vfloat4 r1 = {res[4] - o23.x, res[5] - o23.y, res[6] - o23.z, res[7] - o23.w};
        __builtin_nontemporal_store(r0, (vfloat4*)(out + 2 * base));
        __builtin_nontemporal_store(r1, (vfloat4*)(out + 2 * base + 4));
    } else {
        for (int i = base; i < n; ++i) {
            vfloat4 P  = points_pad[pidx[i]];
            vfloat4 QA = sposes[2 * cidx[i]];
            vfloat4 QB = sposes[2 * cidx[i] + 1];
            float px = P.x, py = P.y, pz = P.z;
            float tx = QA.x, ty = QA.y, tz = QA.z;
            float qx = QA.w, qy = QB.x, qz = QB.y, qw = QB.z;

            float ux = qy * pz - qz * py;
            float uy = qz * px - qx * pz;
            float uz = qx * py - qy * px;
            float wx = ux + qw * px;
            float wy = uy + qw * py;
            float wz = uz + qw * pz;
            float ccx = qy * wz - qz * wy;
            float ccy = qz * wx - qx * wz;
            float ccz = qx * wy - qy * wx;
            float X = px + 2.0f * ccx + tx;
            float Y = py + 2.0f * ccy + ty;
            float Z = pz + 2.0f * ccz + tz;

            float invz = 1.0f / Z;
            out[2 * i]     = fx * X * invz + cx - obs[2 * i];
            out[2 * i + 1] = fy * Y * invz + cy - obs[2 * i + 1];
        }
    }
}

// fallback (ws too small / too many cameras): scalar gathers from raw tables
__global__ __launch_bounds__(256) void resid_fallback(
    const float* __restrict__ obs, const float* __restrict__ Kmat,
    const float* __restrict__ poses, const float* __restrict__ points,
    const int* __restrict__ cidx, const int* __restrict__ pidx,
    float* __restrict__ out, int n)
{
    int i = blockIdx.x * blockDim.x + threadIdx.x;
    if (i >= n) return;
    const float* ps = poses + 7 * cidx[i];
    const float* pt = points + 3 * pidx[i];
    float px = pt[0], py = pt[1], pz = pt[2];
    float tx = ps[0], ty = ps[1], tz = ps[2];
    float qx = ps[3], qy = ps[4], qz = ps[5], qw = ps[6];
    float ux = qy * pz - qz * py;
    float uy = qz * px - qx * pz;
    float uz = qx * py - qy * px;
    float wx = ux + qw * px;
    float wy = uy + qw * py;
    float wz = uz + qw * pz;
    float ccx = qy * wz - qz * wy;
    float ccy = qz * wx - qx * wz;
    float ccz = qx * wy - qy * wx;
    float X = px + 2.0f * ccx + tx;
    float Y = py + 2.0f * ccy + ty;
    float Z = pz + 2.0f * ccz + tz;
    float invz = 1.0f / Z;
    out[2 * i]     = Kmat[0] * X * invz + Kmat[2] - obs[2 * i];
    out[2 * i + 1] = Kmat[4] * Y * invz + Kmat[5] - obs[2 * i + 1];
}

extern "C" void kernel_launch(void* const* d_in, const int* in_sizes, int n_in,
                              void* d_out, int out_size, void* d_ws, size_t ws_size,
                              hipStream_t stream) {
    const float* obs    = (const float*)d_in[0];
    const float* Kmat   = (const float*)d_in[1];
    const float* poses  = (const float*)d_in[2];
    const float* points = (const float*)d_in[3];
    const int*   cidx   = (const int*)d_in[4];
    const int*   pidx   = (const int*)d_in[5];
    float*       out    = (float*)d_out;

    int n     = in_sizes[4];      // N_OBS
    int n_cam = in_sizes[2] / 7;  // 2000
    int n_pts = in_sizes[3] / 3;  // 500000

    size_t pts_bytes  = (size_t)n_pts * 16;
    size_t pose_bytes = (size_t)n_cam * 32;

    if (ws_size < pts_bytes + pose_bytes || n_cam > MAX_CAM) {
        resid_fallback<<<(n + 255) / 256, 256, 0, stream>>>(
            obs, Kmat, poses, points, cidx, pidx, out, n);
        return;
    }

    vfloat4* points_pad = (vfloat4*)d_ws;
    vfloat4* poses_pad  = (vfloat4*)((char*)d_ws + pts_bytes);

    pad_points<<<(n_pts + 255) / 256, 256, 0, stream>>>(points, points_pad, n_pts);
    pad_poses<<<(n_cam + 255) / 256, 256, 0, stream>>>(poses, poses_pad, n_cam);

    int block = 1024;
    int per_block = block * 4;
    int grid = (n + per_block - 1) / per_block;
    resid_lds<<<grid, block, 0, stream>>>(
        obs, Kmat, poses_pad, points_pad, cidx, pidx, out, n, n_cam);
}